// Round 15
// baseline (224.236 us; speedup 1.0000x reference)
//
#include <hip/hip_runtime.h>

#define DIV_UP(a,b) (((a)+(b)-1)/(b))

// bucket = tgt >> 7  (128 nodes per bucket)
constexpr int BSHIFT = 7;
constexpr int BNODES = 128;
constexpr int CHUNK_E = 16384;   // edges per partition block (measured best)
constexpr int PTH = 512;         // partition block threads
constexpr int SCH = 8;           // source chunks for CSR segment ordering
constexpr int SCSH = 14;         // src >> 14 -> chunk id (16K nodes per chunk)

// ---------------- bf16 helpers (storage only; all math fp32) ----------------
__device__ inline unsigned short f2bf(float f) {
    unsigned u = __float_as_uint(f);
    u = u + 0x7FFFu + ((u >> 16) & 1u);   // round-to-nearest-even
    return (unsigned short)(u >> 16);
}
__device__ inline float bflo(unsigned u) { return __uint_as_float(u << 16); }
__device__ inline float bfhi(unsigned u) { return __uint_as_float(u & 0xFFFF0000u); }

// ---------------- CSR build ----------------
__global__ void zero_int_k(int* p, int n) {
    int i = blockIdx.x * blockDim.x + threadIdx.x;
    if (i < n) p[i] = 0;
}

__global__ void bucket_hist_k(const int* __restrict__ col, int* __restrict__ bhist, int E, int nb) {
    __shared__ int lh[1024];
    for (int i = threadIdx.x; i < 1024; i += blockDim.x) lh[i] = 0;
    __syncthreads();
    int stride = gridDim.x * blockDim.x;
    for (int e = blockIdx.x * blockDim.x + threadIdx.x; e < E; e += stride)
        atomicAdd(&lh[col[e] >> BSHIFT], 1);
    __syncthreads();
    for (int i = threadIdx.x; i < nb; i += blockDim.x) {
        int v = lh[i];
        if (v) atomicAdd(&bhist[i], v);
    }
}

__global__ void bucket_scan_k(const int* __restrict__ bhist, int* __restrict__ bcur, int nb) {
    __shared__ int lds[256];
    int base = threadIdx.x * 4;
    int v[4]; int s = 0;
#pragma unroll
    for (int j = 0; j < 4; j++) { v[j] = (base + j < nb) ? bhist[base + j] : 0; s += v[j]; }
    lds[threadIdx.x] = s; __syncthreads();
    for (int off = 1; off < 256; off <<= 1) {
        int t = (threadIdx.x >= off) ? lds[threadIdx.x - off] : 0;
        __syncthreads();
        lds[threadIdx.x] += t;
        __syncthreads();
    }
    int excl = lds[threadIdx.x] - s;
#pragma unroll
    for (int j = 0; j < 4; j++) {
        if (base + j < nb) bcur[base + j] = excl;
        excl += v[j];
    }
}

__global__ void __launch_bounds__(PTH) partition_k(
        const int* __restrict__ row, const int* __restrict__ col,
        int* __restrict__ bcur, int* __restrict__ part, int E, int nb) {
    __shared__ int lh[1024];
    __shared__ int lbase[1024];
    __shared__ int delta[1024];
    __shared__ unsigned sorted[CHUNK_E];
    __shared__ unsigned short bid[CHUNK_E];
    int tid = threadIdx.x;
    for (int i = tid; i < 1024; i += PTH) lh[i] = 0;
    __syncthreads();
    int base = blockIdx.x * CHUNK_E;
    int end = min(E, base + CHUNK_E);
    for (int e = base + tid; e < end; e += PTH)
        atomicAdd(&lh[col[e] >> BSHIFT], 1);
    __syncthreads();
    int v0 = lh[2 * tid], v1 = lh[2 * tid + 1];
    int s = v0 + v1;
    delta[tid] = s;
    __syncthreads();
    for (int off = 1; off < PTH; off <<= 1) {
        int t = (tid >= off) ? delta[tid - off] : 0;
        __syncthreads();
        delta[tid] += t;
        __syncthreads();
    }
    int excl = delta[tid] - s;
    lbase[2 * tid] = excl;
    lbase[2 * tid + 1] = excl + v0;
    __syncthreads();
    for (int i = tid; i < nb; i += PTH) {
        int c = lh[i];
        int g = c ? atomicAdd(&bcur[i], c) : 0;
        delta[i] = g - lbase[i];
    }
    __syncthreads();
    for (int i = tid; i < nb; i += PTH) lh[i] = lbase[i];
    __syncthreads();
    for (int e = base + tid; e < end; e += PTH) {
        int r = row[e], c = col[e];
        int b = c >> BSHIFT;
        int slot = atomicAdd(&lh[b], 1);
        sorted[slot] = (unsigned)((r << BSHIFT) | (c & (BNODES - 1)));
        bid[slot] = (unsigned short)b;
    }
    __syncthreads();
    int cnt = end - base;
    for (int i = tid; i < cnt; i += PTH) {
        int b = bid[i];
        part[delta[b] + i] = (int)sorted[i];
    }
}

__global__ void __launch_bounds__(256) csr_build_k(
        const int* __restrict__ part, const int* __restrict__ bcur,
        int* __restrict__ cur, float* __restrict__ dinv,
        int* __restrict__ csr, int N) {
    __shared__ int cnt[BNODES * SCH];
    __shared__ int scan_t[256];
    __shared__ int ebounds[2];
    int b = blockIdx.x;
    int tid = threadIdx.x;
    if (tid == 0) { ebounds[0] = b ? bcur[b - 1] : 0; ebounds[1] = bcur[b]; }
    for (int i = tid; i < BNODES * SCH; i += 256) cnt[i] = 0;
    __syncthreads();
    int e0 = ebounds[0], e1 = ebounds[1];
    for (int e = e0 + tid; e < e1; e += 256) {
        unsigned v = (unsigned)part[e];
        int cell = (int)(v & (BNODES - 1)) * SCH + (int)(v >> (BSHIFT + SCSH));
        atomicAdd(&cnt[cell], 1);
    }
    __syncthreads();
    int base4 = tid * 4;
    int c0 = cnt[base4], c1 = cnt[base4+1], c2 = cnt[base4+2], c3 = cnt[base4+3];
    int s = c0 + c1 + c2 + c3;
    scan_t[tid] = s;
    __syncthreads();
    for (int off = 1; off < 256; off <<= 1) {
        int t = (tid >= off) ? scan_t[tid - off] : 0;
        __syncthreads();
        scan_t[tid] += t;
        __syncthreads();
    }
    int excl = scan_t[tid] - s;
    cnt[base4]     = excl;
    cnt[base4 + 1] = excl + c0;
    cnt[base4 + 2] = excl + c0 + c1;
    cnt[base4 + 3] = excl + c0 + c1 + c2;
    __syncthreads();
    if (tid < BNODES) {
        int node = b * BNODES + tid;
        int segstart = cnt[tid * SCH];
        int segend   = (tid == BNODES - 1) ? (e1 - e0) : cnt[(tid + 1) * SCH];
        if (node < N) {
            cur[node]  = e0 + segend;
            dinv[node] = rsqrtf(1.0f + (float)(segend - segstart));
        }
    }
    __syncthreads();
    for (int e = e0 + tid; e < e1; e += 256) {
        unsigned v = (unsigned)part[e];
        int cell = (int)(v & (BNODES - 1)) * SCH + (int)(v >> (BSHIFT + SCSH));
        int p = atomicAdd(&cnt[cell], 1);
        csr[e0 + p] = (int)(v >> BSHIFT);
    }
}

// 8-deep gather macro body: accumulates a0..a7 from hb4 rows (stride ST uint4/row, lane off LO)
#define GATHER8(hb4, csr, eS, eE, ST, LO)                                     \
    {                                                                          \
        int e = eS;                                                            \
        for (; e + 7 < eE; e += 8) {                                           \
            int ss[8]; uint4 vv[8];                                            \
            _Pragma("unroll")                                                  \
            for (int u = 0; u < 8; u++) ss[u] = csr[e + u];                    \
            _Pragma("unroll")                                                  \
            for (int u = 0; u < 8; u++) vv[u] = hb4[(size_t)ss[u] * ST + LO];  \
            _Pragma("unroll")                                                  \
            for (int u = 0; u < 8; u++) {                                      \
                a0 += bflo(vv[u].x); a1 += bfhi(vv[u].x);                      \
                a2 += bflo(vv[u].y); a3 += bfhi(vv[u].y);                      \
                a4 += bflo(vv[u].z); a5 += bfhi(vv[u].z);                      \
                a6 += bflo(vv[u].w); a7 += bfhi(vv[u].w);                      \
            }                                                                  \
        }                                                                      \
        if (e + 3 < eE) {                                                      \
            int ss[4]; uint4 vv[4];                                            \
            _Pragma("unroll")                                                  \
            for (int u = 0; u < 4; u++) ss[u] = csr[e + u];                    \
            _Pragma("unroll")                                                  \
            for (int u = 0; u < 4; u++) vv[u] = hb4[(size_t)ss[u] * ST + LO];  \
            _Pragma("unroll")                                                  \
            for (int u = 0; u < 4; u++) {                                      \
                a0 += bflo(vv[u].x); a1 += bfhi(vv[u].x);                      \
                a2 += bflo(vv[u].y); a3 += bfhi(vv[u].y);                      \
                a4 += bflo(vv[u].z); a5 += bfhi(vv[u].z);                      \
                a6 += bflo(vv[u].w); a7 += bfhi(vv[u].w);                      \
            }                                                                  \
            e += 4;                                                            \
        }                                                                      \
        for (; e < eE; e++) {                                                  \
            uint4 v = hb4[(size_t)csr[e] * ST + LO];                           \
            a0 += bflo(v.x); a1 += bfhi(v.x); a2 += bflo(v.y); a3 += bfhi(v.y);\
            a4 += bflo(v.z); a5 += bfhi(v.z); a6 += bflo(v.w); a7 += bfhi(v.w);\
        }                                                                      \
    }

// ---------------- gather, bf16 D=16, EPI1; 8 thr/node (4 contiguous slices) ----------
__global__ void __launch_bounds__(256) gather16_bf_k(
        const unsigned short* __restrict__ hb, const float* __restrict__ dinv,
        const int* __restrict__ cur, const int* __restrict__ csr,
        const float* __restrict__ b, unsigned short* __restrict__ outb, int n) {
    int tid = blockIdx.x * 256 + threadIdx.x;
    int node = tid >> 3, sub = tid & 7;
    int rh = sub & 1, sl = sub >> 1;      // row half (16B), contiguous slice 0..3
    if (node >= n) return;
    const uint4* hb4 = reinterpret_cast<const uint4*>(hb);
    float a0 = 0.f, a1 = 0.f, a2 = 0.f, a3 = 0.f, a4 = 0.f, a5 = 0.f, a6 = 0.f, a7 = 0.f;
    if (sl == 0) {
        uint4 sv = hb4[(size_t)node * 2 + rh];
        a0 = bflo(sv.x); a1 = bfhi(sv.x); a2 = bflo(sv.y); a3 = bfhi(sv.y);
        a4 = bflo(sv.z); a5 = bfhi(sv.z); a6 = bflo(sv.w); a7 = bfhi(sv.w);
    }
    int e0 = node ? cur[node - 1] : 0;
    int e1 = cur[node];
    int len = e1 - e0;
    int eS = e0 + ((len * sl) >> 2);
    int eE = e0 + ((len * (sl + 1)) >> 2);
    GATHER8(hb4, csr, eS, eE, 2, rh)
    a0 += __shfl_xor(a0, 2); a1 += __shfl_xor(a1, 2); a2 += __shfl_xor(a2, 2); a3 += __shfl_xor(a3, 2);
    a4 += __shfl_xor(a4, 2); a5 += __shfl_xor(a5, 2); a6 += __shfl_xor(a6, 2); a7 += __shfl_xor(a7, 2);
    a0 += __shfl_xor(a0, 4); a1 += __shfl_xor(a1, 4); a2 += __shfl_xor(a2, 4); a3 += __shfl_xor(a3, 4);
    a4 += __shfl_xor(a4, 4); a5 += __shfl_xor(a5, 4); a6 += __shfl_xor(a6, 4); a7 += __shfl_xor(a7, 4);
    if (sl != 0) return;
    float di = dinv[node];
    int bo = rh * 8;
    a0 = fmaxf(a0 * di + b[bo+0], 0.f) * di; a1 = fmaxf(a1 * di + b[bo+1], 0.f) * di;
    a2 = fmaxf(a2 * di + b[bo+2], 0.f) * di; a3 = fmaxf(a3 * di + b[bo+3], 0.f) * di;
    a4 = fmaxf(a4 * di + b[bo+4], 0.f) * di; a5 = fmaxf(a5 * di + b[bo+5], 0.f) * di;
    a6 = fmaxf(a6 * di + b[bo+6], 0.f) * di; a7 = fmaxf(a7 * di + b[bo+7], 0.f) * di;
    uint4 pk;
    pk.x = (unsigned)f2bf(a0) | ((unsigned)f2bf(a1) << 16);
    pk.y = (unsigned)f2bf(a2) | ((unsigned)f2bf(a3) << 16);
    pk.z = (unsigned)f2bf(a4) | ((unsigned)f2bf(a5) << 16);
    pk.w = (unsigned)f2bf(a6) | ((unsigned)f2bf(a7) << 16);
    reinterpret_cast<uint4*>(outb)[(size_t)node * 2 + rh] = pk;
}

// ---------------- FUSED gather(D=16) + matmul 16->32 ; 4 thr/node, TN=64 --------------
__global__ void __launch_bounds__(256) gmm16_32_k(
        const unsigned short* __restrict__ hb, const float* __restrict__ dinv,
        const int* __restrict__ cur, const int* __restrict__ csr,
        const float* __restrict__ W, const float* __restrict__ b,
        unsigned short* __restrict__ yb, int n) {
    constexpr int TN = 64, RS = 20;
    __shared__ float xs[TN * RS];
    __shared__ float Ws[16 * 32];
    __shared__ float bs[32];
    for (int i = threadIdx.x; i < 16 * 32; i += 256) Ws[i] = W[i];
    if (threadIdx.x < 32) bs[threadIdx.x] = b[threadIdx.x];
    int base = blockIdx.x * TN;
    {
        int nl = threadIdx.x >> 2, sub = threadIdx.x & 3;
        int rh = sub & 1, sl = sub >> 1;   // row half, contiguous half-slice
        int node = base + nl;
        if (node < n) {
            const uint4* hb4 = reinterpret_cast<const uint4*>(hb);
            float a0 = 0.f, a1 = 0.f, a2 = 0.f, a3 = 0.f, a4 = 0.f, a5 = 0.f, a6 = 0.f, a7 = 0.f;
            if (sl == 0) {
                uint4 sv = hb4[(size_t)node * 2 + rh];
                a0 = bflo(sv.x); a1 = bfhi(sv.x); a2 = bflo(sv.y); a3 = bfhi(sv.y);
                a4 = bflo(sv.z); a5 = bfhi(sv.z); a6 = bflo(sv.w); a7 = bfhi(sv.w);
            }
            int e0 = node ? cur[node - 1] : 0;
            int e1 = cur[node];
            int len = e1 - e0;
            int eS = e0 + ((len * sl) >> 1);
            int eE = e0 + ((len * (sl + 1)) >> 1);
            GATHER8(hb4, csr, eS, eE, 2, rh)
            a0 += __shfl_xor(a0, 2); a1 += __shfl_xor(a1, 2); a2 += __shfl_xor(a2, 2); a3 += __shfl_xor(a3, 2);
            a4 += __shfl_xor(a4, 2); a5 += __shfl_xor(a5, 2); a6 += __shfl_xor(a6, 2); a7 += __shfl_xor(a7, 2);
            if (sl == 0) {
                float di = dinv[node];
                float* dst = &xs[nl * RS + rh * 8];
                dst[0] = a0*di; dst[1] = a1*di; dst[2] = a2*di; dst[3] = a3*di;
                dst[4] = a4*di; dst[5] = a5*di; dst[6] = a6*di; dst[7] = a7*di;
            }
        }
    }
    __syncthreads();
    int nl = threadIdx.x >> 2, g = threadIdx.x & 3;
    int node = base + nl;
    if (node >= n) return;
    int j0 = g * 8;
    float acc[8];
#pragma unroll
    for (int j = 0; j < 8; j++) acc[j] = 0.f;
    const float* xrow = &xs[nl * RS];
#pragma unroll
    for (int k4 = 0; k4 < 4; k4++) {
        float4 xv = *reinterpret_cast<const float4*>(&xrow[k4 * 4]);
        float xk[4] = {xv.x, xv.y, xv.z, xv.w};
#pragma unroll
        for (int kk = 0; kk < 4; kk++) {
            const float* wrow = &Ws[(k4*4+kk) * 32 + j0];
#pragma unroll
            for (int j = 0; j < 8; j++) acc[j] += xk[kk] * wrow[j];
        }
    }
    float di = dinv[node];
    float o[8];
#pragma unroll
    for (int j = 0; j < 8; j++) o[j] = fmaxf(acc[j] + bs[j0 + j], 0.f) * di;
    uint4 pk;
    pk.x = (unsigned)f2bf(o[0]) | ((unsigned)f2bf(o[1]) << 16);
    pk.y = (unsigned)f2bf(o[2]) | ((unsigned)f2bf(o[3]) << 16);
    pk.z = (unsigned)f2bf(o[4]) | ((unsigned)f2bf(o[5]) << 16);
    pk.w = (unsigned)f2bf(o[6]) | ((unsigned)f2bf(o[7]) << 16);
    *reinterpret_cast<uint4*>(yb + (size_t)node * 32 + j0) = pk;
}

// ---------------- FUSED gather(D=32) + matmul 32->64 ; 8 thr/node, TN=32 --------------
__global__ void __launch_bounds__(256) gmm32_64_k(
        const unsigned short* __restrict__ hb, const float* __restrict__ dinv,
        const int* __restrict__ cur, const int* __restrict__ csr,
        const float* __restrict__ W, const float* __restrict__ b,
        unsigned short* __restrict__ yb, int n) {
    constexpr int TN = 32, RS = 36;
    __shared__ float xs[TN * RS];
    __shared__ float Ws[32 * 64];
    __shared__ float bs[64];
    for (int i = threadIdx.x; i < 32 * 64; i += 256) Ws[i] = W[i];
    if (threadIdx.x < 64) bs[threadIdx.x] = b[threadIdx.x];
    int base = blockIdx.x * TN;
    {
        int nl = threadIdx.x >> 3, sub = threadIdx.x & 7;
        int rq = sub & 3, sl = sub >> 2;   // row quarter (16B), contiguous half-slice
        int node = base + nl;
        if (node < n) {
            const uint4* hb4 = reinterpret_cast<const uint4*>(hb);
            float a0 = 0.f, a1 = 0.f, a2 = 0.f, a3 = 0.f, a4 = 0.f, a5 = 0.f, a6 = 0.f, a7 = 0.f;
            if (sl == 0) {
                uint4 sv = hb4[(size_t)node * 4 + rq];
                a0 = bflo(sv.x); a1 = bfhi(sv.x); a2 = bflo(sv.y); a3 = bfhi(sv.y);
                a4 = bflo(sv.z); a5 = bfhi(sv.z); a6 = bflo(sv.w); a7 = bfhi(sv.w);
            }
            int e0 = node ? cur[node - 1] : 0;
            int e1 = cur[node];
            int len = e1 - e0;
            int eS = e0 + ((len * sl) >> 1);
            int eE = e0 + ((len * (sl + 1)) >> 1);
            GATHER8(hb4, csr, eS, eE, 4, rq)
            a0 += __shfl_xor(a0, 4); a1 += __shfl_xor(a1, 4); a2 += __shfl_xor(a2, 4); a3 += __shfl_xor(a3, 4);
            a4 += __shfl_xor(a4, 4); a5 += __shfl_xor(a5, 4); a6 += __shfl_xor(a6, 4); a7 += __shfl_xor(a7, 4);
            if (sl == 0) {
                float di = dinv[node];
                float* dst = &xs[nl * RS + rq * 8];
                dst[0] = a0*di; dst[1] = a1*di; dst[2] = a2*di; dst[3] = a3*di;
                dst[4] = a4*di; dst[5] = a5*di; dst[6] = a6*di; dst[7] = a7*di;
            }
        }
    }
    __syncthreads();
    int nl = threadIdx.x >> 3, g = threadIdx.x & 7;
    int node = base + nl;
    if (node >= n) return;
    int j0 = g * 8;
    float acc[8];
#pragma unroll
    for (int j = 0; j < 8; j++) acc[j] = 0.f;
    const float* xrow = &xs[nl * RS];
#pragma unroll
    for (int k4 = 0; k4 < 8; k4++) {
        float4 xv = *reinterpret_cast<const float4*>(&xrow[k4 * 4]);
        float xk[4] = {xv.x, xv.y, xv.z, xv.w};
#pragma unroll
        for (int kk = 0; kk < 4; kk++) {
            const float* wrow = &Ws[(k4*4+kk) * 64 + j0];
#pragma unroll
            for (int j = 0; j < 8; j++) acc[j] += xk[kk] * wrow[j];
        }
    }
    float di = dinv[node];
    float o[8];
#pragma unroll
    for (int j = 0; j < 8; j++) o[j] = fmaxf(acc[j] + bs[j0 + j], 0.f) * di;
    uint4 pk;
    pk.x = (unsigned)f2bf(o[0]) | ((unsigned)f2bf(o[1]) << 16);
    pk.y = (unsigned)f2bf(o[2]) | ((unsigned)f2bf(o[3]) << 16);
    pk.z = (unsigned)f2bf(o[4]) | ((unsigned)f2bf(o[5]) << 16);
    pk.w = (unsigned)f2bf(o[6]) | ((unsigned)f2bf(o[7]) << 16);
    *reinterpret_cast<uint4*>(yb + (size_t)node * 64 + j0) = pk;
}

// ---------------- pooling helpers ----------------
__device__ inline unsigned fkey(float x) {
    unsigned u = __float_as_uint(x);
    return (u & 0x80000000u) ? ~u : (u | 0x80000000u);
}
__device__ inline float funkey(unsigned k) {
    unsigned u = (k & 0x80000000u) ? (k & 0x7FFFFFFFu) : ~k;
    return __uint_as_float(u);
}

// ---------------- fused final gather (D=4) + segment-max pool ; 8 thr/node -----------
__global__ void gather4_pool_k(const float* __restrict__ hs, const float* __restrict__ dinv,
                               const int* __restrict__ cur, const int* __restrict__ csr,
                               const float* __restrict__ b4, const int* __restrict__ batch,
                               unsigned* __restrict__ pooled, int n, int num_graphs) {
    __shared__ unsigned lds[128 * 4];
    for (int i = threadIdx.x; i < num_graphs * 4; i += blockDim.x) lds[i] = 0u;
    __syncthreads();
    int tid = blockIdx.x * blockDim.x + threadIdx.x;
    int node = tid >> 3, sl = tid & 7;     // 8 contiguous edge slices
    if (node < n) {
        float4 acc = make_float4(0.f, 0.f, 0.f, 0.f);
        if (sl == 0) acc = reinterpret_cast<const float4*>(hs)[node];
        int e0 = node ? cur[node - 1] : 0;
        int e1 = cur[node];
        int len = e1 - e0;
        int eS = e0 + ((len * sl) >> 3);
        int eE = e0 + ((len * (sl + 1)) >> 3);
        int e = eS;
        for (; e + 3 < eE; e += 4) {
            int s0 = csr[e], s1 = csr[e+1], s2 = csr[e+2], s3 = csr[e+3];
            float4 v0 = reinterpret_cast<const float4*>(hs)[s0];
            float4 v1 = reinterpret_cast<const float4*>(hs)[s1];
            float4 v2 = reinterpret_cast<const float4*>(hs)[s2];
            float4 v3 = reinterpret_cast<const float4*>(hs)[s3];
            acc.x += (v0.x + v1.x) + (v2.x + v3.x);
            acc.y += (v0.y + v1.y) + (v2.y + v3.y);
            acc.z += (v0.z + v1.z) + (v2.z + v3.z);
            acc.w += (v0.w + v1.w) + (v2.w + v3.w);
        }
        for (; e < eE; e++) {
            float4 v0 = reinterpret_cast<const float4*>(hs)[csr[e]];
            acc.x += v0.x; acc.y += v0.y; acc.z += v0.z; acc.w += v0.w;
        }
#pragma unroll
        for (int m = 1; m <= 4; m <<= 1) {
            acc.x += __shfl_xor(acc.x, m);
            acc.y += __shfl_xor(acc.y, m);
            acc.z += __shfl_xor(acc.z, m);
            acc.w += __shfl_xor(acc.w, m);
        }
        if (sl == 0) {
            float di = dinv[node];
            int g = batch[node];
            atomicMax(&lds[g*4+0], fkey(acc.x * di + b4[0]));
            atomicMax(&lds[g*4+1], fkey(acc.y * di + b4[1]));
            atomicMax(&lds[g*4+2], fkey(acc.z * di + b4[2]));
            atomicMax(&lds[g*4+3], fkey(acc.w * di + b4[3]));
        }
    }
    __syncthreads();
    for (int i2 = threadIdx.x; i2 < num_graphs * 4; i2 += blockDim.x) {
        unsigned k = lds[i2];
        if (k) atomicMax(&pooled[i2], k);
    }
}

__global__ void pool_init_k(unsigned* pooled, int total) {
    int i = blockIdx.x * blockDim.x + threadIdx.x;
    if (i < total) pooled[i] = 0u;
}

__global__ void logsoftmax_k(const unsigned* __restrict__ pooled, float* __restrict__ out, int G) {
    int g = blockIdx.x * blockDim.x + threadIdx.x;
    if (g >= G) return;
    float v[4];
#pragma unroll
    for (int j = 0; j < 4; j++) v[j] = funkey(pooled[g*4+j]);
    float m = fmaxf(fmaxf(v[0], v[1]), fmaxf(v[2], v[3]));
    float s = 0.f;
#pragma unroll
    for (int j = 0; j < 4; j++) s += expf(v[j] - m);
    float l = logf(s);
#pragma unroll
    for (int j = 0; j < 4; j++) out[g*4+j] = v[j] - m - l;
}

// ---------------- LDS-tiled skinny matmul with optional bf16 in/out ----------------
template<int IN, int OUT, bool RELU, bool BIAS, bool SCALE, bool IBF, bool OBF>
__global__ void __launch_bounds__(256) matmul_k(
        const void* __restrict__ xv, const float* __restrict__ W,
        const float* __restrict__ b, const float* __restrict__ dinv,
        void* __restrict__ yv, int n) {
    constexpr int TN  = 64;
    constexpr int RS  = IN + 4;
    constexpr int OPT = OUT / 4;
    constexpr int NQ  = IN / 4;
    __shared__ float xs[TN * RS];
    __shared__ float Ws[IN * OUT];
    __shared__ float bs[OUT];

    for (int i = threadIdx.x; i < IN * OUT; i += 256) Ws[i] = W[i];
    if (BIAS) for (int i = threadIdx.x; i < OUT; i += 256) bs[i] = b[i];

    int base = blockIdx.x * TN;
    if constexpr (!IBF) {
        const float* x = (const float*)xv;
        for (int i = threadIdx.x; i < TN * NQ; i += 256) {
            int r = i / NQ, c = i % NQ;
            float4 v = make_float4(0.f, 0.f, 0.f, 0.f);
            if (base + r < n) v = reinterpret_cast<const float4*>(x + (size_t)(base + r) * IN)[c];
            *reinterpret_cast<float4*>(&xs[r * RS + c * 4]) = v;
        }
    } else {
        constexpr int NU = IN / 8;
        const uint4* x = (const uint4*)xv;
        for (int i = threadIdx.x; i < TN * NU; i += 256) {
            int r = i / NU, c = i % NU;
            uint4 v = make_uint4(0u, 0u, 0u, 0u);
            if (base + r < n) v = x[(size_t)(base + r) * NU + c];
            float* dst = &xs[r * RS + c * 8];
            dst[0] = bflo(v.x); dst[1] = bfhi(v.x);
            dst[2] = bflo(v.y); dst[3] = bfhi(v.y);
            dst[4] = bflo(v.z); dst[5] = bfhi(v.z);
            dst[6] = bflo(v.w); dst[7] = bfhi(v.w);
        }
    }
    __syncthreads();

    int node = threadIdx.x >> 2;
    int g    = threadIdx.x & 3;
    int j0   = g * OPT;
    int gnode = base + node;
    if (gnode >= n) return;

    float acc[OPT];
#pragma unroll
    for (int jj = 0; jj < OPT; jj++) acc[jj] = 0.f;

    const float* xrow = &xs[node * RS];
#pragma unroll
    for (int k4 = 0; k4 < NQ; k4++) {
        float4 xvv = *reinterpret_cast<const float4*>(&xrow[k4 * 4]);
        float xk[4] = {xvv.x, xvv.y, xvv.z, xvv.w};
#pragma unroll
        for (int kk = 0; kk < 4; kk++) {
            const float* wrow = &Ws[(k4 * 4 + kk) * OUT + j0];
#pragma unroll
            for (int jj = 0; jj < OPT; jj++)
                acc[jj] += xk[kk] * wrow[jj];
        }
    }

    float di = SCALE ? dinv[gnode] : 1.f;
    float vout[OPT];
#pragma unroll
    for (int jj = 0; jj < OPT; jj++) {
        float v = acc[jj] + (BIAS ? bs[j0 + jj] : 0.f);
        if (RELU) v = fmaxf(v, 0.f);
        if (SCALE) v *= di;
        vout[jj] = v;
    }
    if constexpr (OBF) {
        unsigned short* yr = (unsigned short*)yv + (size_t)gnode * OUT + j0;
        if constexpr (OPT % 8 == 0) {
#pragma unroll
            for (int q = 0; q < OPT / 8; q++) {
                uint4 pk;
                pk.x = (unsigned)f2bf(vout[q*8+0]) | ((unsigned)f2bf(vout[q*8+1]) << 16);
                pk.y = (unsigned)f2bf(vout[q*8+2]) | ((unsigned)f2bf(vout[q*8+3]) << 16);
                pk.z = (unsigned)f2bf(vout[q*8+4]) | ((unsigned)f2bf(vout[q*8+5]) << 16);
                pk.w = (unsigned)f2bf(vout[q*8+6]) | ((unsigned)f2bf(vout[q*8+7]) << 16);
                reinterpret_cast<uint4*>(yr)[q] = pk;
            }
        } else {
            uint2 pk;
            pk.x = (unsigned)f2bf(vout[0]) | ((unsigned)f2bf(vout[1]) << 16);
            pk.y = (unsigned)f2bf(vout[2]) | ((unsigned)f2bf(vout[3]) << 16);
            *reinterpret_cast<uint2*>(yr) = pk;
        }
    } else {
        float* yr = (float*)yv + (size_t)gnode * OUT + j0;
        if (OPT % 4 == 0) {
#pragma unroll
            for (int q = 0; q < OPT / 4; q++)
                *reinterpret_cast<float4*>(yr + q * 4) =
                    make_float4(vout[q*4+0], vout[q*4+1], vout[q*4+2], vout[q*4+3]);
        } else {
#pragma unroll
            for (int jj = 0; jj < OPT; jj++) yr[jj] = vout[jj];
        }
    }
}

// ---------------- launch ----------------
extern "C" void kernel_launch(void* const* d_in, const int* in_sizes, int n_in,
                              void* d_out, int out_size, void* d_ws, size_t ws_size,
                              hipStream_t stream) {
    const float* x     = (const float*)d_in[0];
    const int*   ei    = (const int*)d_in[1];
    const int*   batch = (const int*)d_in[2];
    const float* W1 = (const float*)d_in[3];
    const float* b1 = (const float*)d_in[4];
    const float* W2 = (const float*)d_in[5];
    const float* b2 = (const float*)d_in[6];
    const float* W3 = (const float*)d_in[7];
    const float* b3 = (const float*)d_in[8];
    const float* W4 = (const float*)d_in[9];
    const float* b4 = (const float*)d_in[10];

    const int N = in_sizes[2];          // 100000
    const int E = in_sizes[1] / 2;      // 3.2M
    const int G = 128;
    const int* row = ei;
    const int* col = ei + E;
    const int NB = DIV_UP(N, BNODES);   // 782 buckets

    // workspace layout
    float* ws    = (float*)d_ws;
    float* dinv  = ws;                              // N floats
    int*   cur   = (int*)(dinv + N);                // N ints
    int*   bhist = cur + N;                         // 1024 ints
    int*   bcur  = bhist + 1024;                    // 1024 ints
    int*   csr   = bcur + 1024;                     // E ints
    float* f16a  = (float*)(csr + E);               // N*16 floats region
    float* f16b  = f16a + (size_t)N * 16;           // N*16 floats region
    float* f32a  = f16b + (size_t)N * 16;           // N*32 floats region
    float* f32b  = f32a + (size_t)N * 32;           // N*32 floats region
    unsigned* pooled = (unsigned*)(f32b + (size_t)N * 32);  // 512
    int* part = (int*)f32a;                         // dead after csr_build
    unsigned short* hb16a = (unsigned short*)f16a;  // N*16 bf16
    unsigned short* hb16b = (unsigned short*)f16b;  // N*16 bf16
    unsigned short* hb32  = (unsigned short*)f32a;  // N*32 bf16 (after part dead)
    unsigned short* hb64  = (unsigned short*)f32b;  // N*64 bf16 = f32b region
    float* f4a = f16a;                              // N*4 fp32 (f16a free after gmm16_32)

    const int B = 256;
    const int gridM  = DIV_UP(N, 64);     // matmul_k / gmm16_32: 64 nodes/block
    const int grid32 = DIV_UP(N, 32);     // gmm32_64: 32 nodes/block
    const int grid8  = DIV_UP(8 * N, B);  // 8 threads/node kernels

    // CSR build: hist -> scan -> LDS-ranked partition -> per-bucket (tgt,src-chunk) sort
    zero_int_k<<<DIV_UP(1024, B), B, 0, stream>>>(bhist, 1024);
    bucket_hist_k<<<512, B, 0, stream>>>(col, bhist, E, NB);
    bucket_scan_k<<<1, 256, 0, stream>>>(bhist, bcur, NB);
    partition_k<<<DIV_UP(E, CHUNK_E), PTH, 0, stream>>>(row, col, bcur, part, E, NB);
    csr_build_k<<<NB, 256, 0, stream>>>(part, bcur, cur, dinv, csr, N);

    // L1: y1 = (x@W1)*dinv -> hb16b (bf16) ; gather+bias+relu+scale -> hb16a (bf16)
    matmul_k<128,16,false,false,true,false,true><<<gridM, B, 0, stream>>>(x, W1, nullptr, dinv, hb16b, N);
    gather16_bf_k<<<grid8, B, 0, stream>>>(hb16b, dinv, cur, csr, b1, hb16a, N);

    // L2 fused: gather(hb16a) + matmul 16->32 +b2,relu,*dinv -> hb32 (bf16)
    gmm16_32_k<<<gridM, B, 0, stream>>>(hb16a, dinv, cur, csr, W2, b2, hb32, N);

    // L3 fused: gather(hb32) + matmul 32->64 +b3,relu,*dinv -> hb64 (bf16)
    gmm32_64_k<<<grid32, B, 0, stream>>>(hb32, dinv, cur, csr, W3, b3, hb64, N);

    // L4: y4 = h3s@W4 (bf16 in) -> f4a (fp32) ; fused gather+pool (adds b4)
    matmul_k<64,4,false,false,false,true,false><<<gridM, B, 0, stream>>>(hb64, W4, nullptr, nullptr, f4a, N);
    pool_init_k<<<DIV_UP(G*4, B), B, 0, stream>>>(pooled, G*4);
    gather4_pool_k<<<grid8, B, 0, stream>>>(f4a, dinv, cur, csr, b4, batch, pooled, N, G);

    // log_softmax
    logsoftmax_k<<<1, 128, 0, stream>>>(pooled, (float*)d_out, G);
}

// Round 16
// 218.409 us; speedup vs baseline: 1.0267x; 1.0267x over previous
//
#include <hip/hip_runtime.h>

#define DIV_UP(a,b) (((a)+(b)-1)/(b))

// bucket = tgt >> 7  (128 nodes per bucket)
constexpr int BSHIFT = 7;
constexpr int BNODES = 128;
constexpr int CHUNK_E = 16384;   // edges per partition block (measured best)
constexpr int PTH = 512;         // partition block threads
constexpr int SCH = 8;           // source chunks for CSR segment ordering
constexpr int SCSH = 14;         // src >> 14 -> chunk id (16K nodes per chunk)

// ---------------- bf16 helpers (storage only; all math fp32) ----------------
__device__ inline unsigned short f2bf(float f) {
    unsigned u = __float_as_uint(f);
    u = u + 0x7FFFu + ((u >> 16) & 1u);   // round-to-nearest-even
    return (unsigned short)(u >> 16);
}
__device__ inline float bflo(unsigned u) { return __uint_as_float(u << 16); }
__device__ inline float bfhi(unsigned u) { return __uint_as_float(u & 0xFFFF0000u); }

// ---------------- CSR build ----------------
__global__ void zero_int_k(int* p, int n) {
    int i = blockIdx.x * blockDim.x + threadIdx.x;
    if (i < n) p[i] = 0;
}

__global__ void bucket_hist_k(const int* __restrict__ col, int* __restrict__ bhist, int E, int nb) {
    __shared__ int lh[1024];
    for (int i = threadIdx.x; i < 1024; i += blockDim.x) lh[i] = 0;
    __syncthreads();
    int stride = gridDim.x * blockDim.x;
    for (int e = blockIdx.x * blockDim.x + threadIdx.x; e < E; e += stride)
        atomicAdd(&lh[col[e] >> BSHIFT], 1);
    __syncthreads();
    for (int i = threadIdx.x; i < nb; i += blockDim.x) {
        int v = lh[i];
        if (v) atomicAdd(&bhist[i], v);
    }
}

__global__ void bucket_scan_k(const int* __restrict__ bhist, int* __restrict__ bcur, int nb) {
    __shared__ int lds[256];
    int base = threadIdx.x * 4;
    int v[4]; int s = 0;
#pragma unroll
    for (int j = 0; j < 4; j++) { v[j] = (base + j < nb) ? bhist[base + j] : 0; s += v[j]; }
    lds[threadIdx.x] = s; __syncthreads();
    for (int off = 1; off < 256; off <<= 1) {
        int t = (threadIdx.x >= off) ? lds[threadIdx.x - off] : 0;
        __syncthreads();
        lds[threadIdx.x] += t;
        __syncthreads();
    }
    int excl = lds[threadIdx.x] - s;
#pragma unroll
    for (int j = 0; j < 4; j++) {
        if (base + j < nb) bcur[base + j] = excl;
        excl += v[j];
    }
}

__global__ void __launch_bounds__(PTH) partition_k(
        const int* __restrict__ row, const int* __restrict__ col,
        int* __restrict__ bcur, int* __restrict__ part, int E, int nb) {
    __shared__ int lh[1024];
    __shared__ int lbase[1024];
    __shared__ int delta[1024];
    __shared__ unsigned sorted[CHUNK_E];
    __shared__ unsigned short bid[CHUNK_E];
    int tid = threadIdx.x;
    for (int i = tid; i < 1024; i += PTH) lh[i] = 0;
    __syncthreads();
    int base = blockIdx.x * CHUNK_E;
    int end = min(E, base + CHUNK_E);
    for (int e = base + tid; e < end; e += PTH)
        atomicAdd(&lh[col[e] >> BSHIFT], 1);
    __syncthreads();
    int v0 = lh[2 * tid], v1 = lh[2 * tid + 1];
    int s = v0 + v1;
    delta[tid] = s;
    __syncthreads();
    for (int off = 1; off < PTH; off <<= 1) {
        int t = (tid >= off) ? delta[tid - off] : 0;
        __syncthreads();
        delta[tid] += t;
        __syncthreads();
    }
    int excl = delta[tid] - s;
    lbase[2 * tid] = excl;
    lbase[2 * tid + 1] = excl + v0;
    __syncthreads();
    for (int i = tid; i < nb; i += PTH) {
        int c = lh[i];
        int g = c ? atomicAdd(&bcur[i], c) : 0;
        delta[i] = g - lbase[i];
    }
    __syncthreads();
    for (int i = tid; i < nb; i += PTH) lh[i] = lbase[i];
    __syncthreads();
    for (int e = base + tid; e < end; e += PTH) {
        int r = row[e], c = col[e];
        int b = c >> BSHIFT;
        int slot = atomicAdd(&lh[b], 1);
        sorted[slot] = (unsigned)((r << BSHIFT) | (c & (BNODES - 1)));
        bid[slot] = (unsigned short)b;
    }
    __syncthreads();
    int cnt = end - base;
    for (int i = tid; i < cnt; i += PTH) {
        int b = bid[i];
        part[delta[b] + i] = (int)sorted[i];
    }
}

__global__ void __launch_bounds__(256) csr_build_k(
        const int* __restrict__ part, const int* __restrict__ bcur,
        int* __restrict__ cur, float* __restrict__ dinv,
        int* __restrict__ csr, int N) {
    __shared__ int cnt[BNODES * SCH];
    __shared__ int scan_t[256];
    __shared__ int ebounds[2];
    int b = blockIdx.x;
    int tid = threadIdx.x;
    if (tid == 0) { ebounds[0] = b ? bcur[b - 1] : 0; ebounds[1] = bcur[b]; }
    for (int i = tid; i < BNODES * SCH; i += 256) cnt[i] = 0;
    __syncthreads();
    int e0 = ebounds[0], e1 = ebounds[1];
    for (int e = e0 + tid; e < e1; e += 256) {
        unsigned v = (unsigned)part[e];
        int cell = (int)(v & (BNODES - 1)) * SCH + (int)(v >> (BSHIFT + SCSH));
        atomicAdd(&cnt[cell], 1);
    }
    __syncthreads();
    int base4 = tid * 4;
    int c0 = cnt[base4], c1 = cnt[base4+1], c2 = cnt[base4+2], c3 = cnt[base4+3];
    int s = c0 + c1 + c2 + c3;
    scan_t[tid] = s;
    __syncthreads();
    for (int off = 1; off < 256; off <<= 1) {
        int t = (tid >= off) ? scan_t[tid - off] : 0;
        __syncthreads();
        scan_t[tid] += t;
        __syncthreads();
    }
    int excl = scan_t[tid] - s;
    cnt[base4]     = excl;
    cnt[base4 + 1] = excl + c0;
    cnt[base4 + 2] = excl + c0 + c1;
    cnt[base4 + 3] = excl + c0 + c1 + c2;
    __syncthreads();
    if (tid < BNODES) {
        int node = b * BNODES + tid;
        int segstart = cnt[tid * SCH];
        int segend   = (tid == BNODES - 1) ? (e1 - e0) : cnt[(tid + 1) * SCH];
        if (node < N) {
            cur[node]  = e0 + segend;
            dinv[node] = rsqrtf(1.0f + (float)(segend - segstart));
        }
    }
    __syncthreads();
    for (int e = e0 + tid; e < e1; e += 256) {
        unsigned v = (unsigned)part[e];
        int cell = (int)(v & (BNODES - 1)) * SCH + (int)(v >> (BSHIFT + SCSH));
        int p = atomicAdd(&cnt[cell], 1);
        csr[e0 + p] = (int)(v >> BSHIFT);
    }
}

// ---------------- gather, bf16 D=16, EPI1; 8 threads/node (4 edge slices) ------------
__global__ void __launch_bounds__(256) gather16_bf_k(
        const unsigned short* __restrict__ hb, const float* __restrict__ dinv,
        const int* __restrict__ cur, const int* __restrict__ csr,
        const float* __restrict__ b, unsigned short* __restrict__ outb, int n) {
    int tid = blockIdx.x * 256 + threadIdx.x;
    int node = tid >> 3, sub = tid & 7;
    int rh = sub & 1, p = sub >> 1;       // row half (16B), edge slice 0..3
    if (node >= n) return;
    const uint4* hb4 = reinterpret_cast<const uint4*>(hb);
    float a0 = 0.f, a1 = 0.f, a2 = 0.f, a3 = 0.f, a4 = 0.f, a5 = 0.f, a6 = 0.f, a7 = 0.f;
    if (p == 0) {
        uint4 sv = hb4[(size_t)node * 2 + rh];
        a0 = bflo(sv.x); a1 = bfhi(sv.x); a2 = bflo(sv.y); a3 = bfhi(sv.y);
        a4 = bflo(sv.z); a5 = bfhi(sv.z); a6 = bflo(sv.w); a7 = bfhi(sv.w);
    }
    int e0 = node ? cur[node - 1] : 0;
    int e1 = cur[node];
    int e = e0 + p;
    for (; e + 12 < e1; e += 16) {        // 4 loads in flight per slice
        int s0 = csr[e], s1 = csr[e+4], s2 = csr[e+8], s3 = csr[e+12];
        uint4 v0 = hb4[(size_t)s0 * 2 + rh];
        uint4 v1 = hb4[(size_t)s1 * 2 + rh];
        uint4 v2 = hb4[(size_t)s2 * 2 + rh];
        uint4 v3 = hb4[(size_t)s3 * 2 + rh];
        a0 += (bflo(v0.x) + bflo(v1.x)) + (bflo(v2.x) + bflo(v3.x));
        a1 += (bfhi(v0.x) + bfhi(v1.x)) + (bfhi(v2.x) + bfhi(v3.x));
        a2 += (bflo(v0.y) + bflo(v1.y)) + (bflo(v2.y) + bflo(v3.y));
        a3 += (bfhi(v0.y) + bfhi(v1.y)) + (bfhi(v2.y) + bfhi(v3.y));
        a4 += (bflo(v0.z) + bflo(v1.z)) + (bflo(v2.z) + bflo(v3.z));
        a5 += (bfhi(v0.z) + bfhi(v1.z)) + (bfhi(v2.z) + bfhi(v3.z));
        a6 += (bflo(v0.w) + bflo(v1.w)) + (bflo(v2.w) + bflo(v3.w));
        a7 += (bfhi(v0.w) + bfhi(v1.w)) + (bfhi(v2.w) + bfhi(v3.w));
    }
    for (; e < e1; e += 4) {
        uint4 v = hb4[(size_t)csr[e] * 2 + rh];
        a0 += bflo(v.x); a1 += bfhi(v.x); a2 += bflo(v.y); a3 += bfhi(v.y);
        a4 += bflo(v.z); a5 += bfhi(v.z); a6 += bflo(v.w); a7 += bfhi(v.w);
    }
    // reduce over edge slices (lanes differing in bits 1,2 of tid)
    a0 += __shfl_xor(a0, 2); a1 += __shfl_xor(a1, 2); a2 += __shfl_xor(a2, 2); a3 += __shfl_xor(a3, 2);
    a4 += __shfl_xor(a4, 2); a5 += __shfl_xor(a5, 2); a6 += __shfl_xor(a6, 2); a7 += __shfl_xor(a7, 2);
    a0 += __shfl_xor(a0, 4); a1 += __shfl_xor(a1, 4); a2 += __shfl_xor(a2, 4); a3 += __shfl_xor(a3, 4);
    a4 += __shfl_xor(a4, 4); a5 += __shfl_xor(a5, 4); a6 += __shfl_xor(a6, 4); a7 += __shfl_xor(a7, 4);
    if (p != 0) return;
    float di = dinv[node];
    int bo = rh * 8;
    a0 = fmaxf(a0 * di + b[bo+0], 0.f) * di; a1 = fmaxf(a1 * di + b[bo+1], 0.f) * di;
    a2 = fmaxf(a2 * di + b[bo+2], 0.f) * di; a3 = fmaxf(a3 * di + b[bo+3], 0.f) * di;
    a4 = fmaxf(a4 * di + b[bo+4], 0.f) * di; a5 = fmaxf(a5 * di + b[bo+5], 0.f) * di;
    a6 = fmaxf(a6 * di + b[bo+6], 0.f) * di; a7 = fmaxf(a7 * di + b[bo+7], 0.f) * di;
    uint4 pk;
    pk.x = (unsigned)f2bf(a0) | ((unsigned)f2bf(a1) << 16);
    pk.y = (unsigned)f2bf(a2) | ((unsigned)f2bf(a3) << 16);
    pk.z = (unsigned)f2bf(a4) | ((unsigned)f2bf(a5) << 16);
    pk.w = (unsigned)f2bf(a6) | ((unsigned)f2bf(a7) << 16);
    reinterpret_cast<uint4*>(outb)[(size_t)node * 2 + rh] = pk;
}

// ---------------- FUSED gather(D=16) + matmul 16->32 ; 4 thr/node, TN=64 --------------
__global__ void __launch_bounds__(256) gmm16_32_k(
        const unsigned short* __restrict__ hb, const float* __restrict__ dinv,
        const int* __restrict__ cur, const int* __restrict__ csr,
        const float* __restrict__ W, const float* __restrict__ b,
        unsigned short* __restrict__ yb, int n) {
    constexpr int TN = 64, RS = 20;
    __shared__ float xs[TN * RS];
    __shared__ float Ws[16 * 32];
    __shared__ float bs[32];
    for (int i = threadIdx.x; i < 16 * 32; i += 256) Ws[i] = W[i];
    if (threadIdx.x < 32) bs[threadIdx.x] = b[threadIdx.x];
    int base = blockIdx.x * TN;
    {
        int nl = threadIdx.x >> 2, sub = threadIdx.x & 3;
        int rh = sub & 1, p = sub >> 1;   // row half, edge parity
        int node = base + nl;
        if (node < n) {
            const uint4* hb4 = reinterpret_cast<const uint4*>(hb);
            float a0 = 0.f, a1 = 0.f, a2 = 0.f, a3 = 0.f, a4 = 0.f, a5 = 0.f, a6 = 0.f, a7 = 0.f;
            if (p == 0) {
                uint4 sv = hb4[(size_t)node * 2 + rh];
                a0 = bflo(sv.x); a1 = bfhi(sv.x); a2 = bflo(sv.y); a3 = bfhi(sv.y);
                a4 = bflo(sv.z); a5 = bfhi(sv.z); a6 = bflo(sv.w); a7 = bfhi(sv.w);
            }
            int e0 = node ? cur[node - 1] : 0;
            int e1 = cur[node];
            int e = e0 + p;
            for (; e + 6 < e1; e += 8) {
                int s0 = csr[e], s1 = csr[e+2], s2 = csr[e+4], s3 = csr[e+6];
                uint4 v0 = hb4[(size_t)s0 * 2 + rh];
                uint4 v1 = hb4[(size_t)s1 * 2 + rh];
                uint4 v2 = hb4[(size_t)s2 * 2 + rh];
                uint4 v3 = hb4[(size_t)s3 * 2 + rh];
                a0 += (bflo(v0.x) + bflo(v1.x)) + (bflo(v2.x) + bflo(v3.x));
                a1 += (bfhi(v0.x) + bfhi(v1.x)) + (bfhi(v2.x) + bfhi(v3.x));
                a2 += (bflo(v0.y) + bflo(v1.y)) + (bflo(v2.y) + bflo(v3.y));
                a3 += (bfhi(v0.y) + bfhi(v1.y)) + (bfhi(v2.y) + bfhi(v3.y));
                a4 += (bflo(v0.z) + bflo(v1.z)) + (bflo(v2.z) + bflo(v3.z));
                a5 += (bfhi(v0.z) + bfhi(v1.z)) + (bfhi(v2.z) + bfhi(v3.z));
                a6 += (bflo(v0.w) + bflo(v1.w)) + (bflo(v2.w) + bflo(v3.w));
                a7 += (bfhi(v0.w) + bfhi(v1.w)) + (bfhi(v2.w) + bfhi(v3.w));
            }
            for (; e < e1; e += 2) {
                uint4 v = hb4[(size_t)csr[e] * 2 + rh];
                a0 += bflo(v.x); a1 += bfhi(v.x); a2 += bflo(v.y); a3 += bfhi(v.y);
                a4 += bflo(v.z); a5 += bfhi(v.z); a6 += bflo(v.w); a7 += bfhi(v.w);
            }
            a0 += __shfl_xor(a0, 2); a1 += __shfl_xor(a1, 2); a2 += __shfl_xor(a2, 2); a3 += __shfl_xor(a3, 2);
            a4 += __shfl_xor(a4, 2); a5 += __shfl_xor(a5, 2); a6 += __shfl_xor(a6, 2); a7 += __shfl_xor(a7, 2);
            if (p == 0) {
                float di = dinv[node];
                float* dst = &xs[nl * RS + rh * 8];
                dst[0] = a0*di; dst[1] = a1*di; dst[2] = a2*di; dst[3] = a3*di;
                dst[4] = a4*di; dst[5] = a5*di; dst[6] = a6*di; dst[7] = a7*di;
            }
        }
    }
    __syncthreads();
    // matmul: 4 threads/node, 8 outputs each
    int nl = threadIdx.x >> 2, g = threadIdx.x & 3;
    int node = base + nl;
    if (node >= n) return;
    int j0 = g * 8;
    float acc[8];
#pragma unroll
    for (int j = 0; j < 8; j++) acc[j] = 0.f;
    const float* xrow = &xs[nl * RS];
#pragma unroll
    for (int k4 = 0; k4 < 4; k4++) {
        float4 xv = *reinterpret_cast<const float4*>(&xrow[k4 * 4]);
        float xk[4] = {xv.x, xv.y, xv.z, xv.w};
#pragma unroll
        for (int kk = 0; kk < 4; kk++) {
            const float* wrow = &Ws[(k4*4+kk) * 32 + j0];
#pragma unroll
            for (int j = 0; j < 8; j++) acc[j] += xk[kk] * wrow[j];
        }
    }
    float di = dinv[node];
    float o[8];
#pragma unroll
    for (int j = 0; j < 8; j++) o[j] = fmaxf(acc[j] + bs[j0 + j], 0.f) * di;
    uint4 pk;
    pk.x = (unsigned)f2bf(o[0]) | ((unsigned)f2bf(o[1]) << 16);
    pk.y = (unsigned)f2bf(o[2]) | ((unsigned)f2bf(o[3]) << 16);
    pk.z = (unsigned)f2bf(o[4]) | ((unsigned)f2bf(o[5]) << 16);
    pk.w = (unsigned)f2bf(o[6]) | ((unsigned)f2bf(o[7]) << 16);
    *reinterpret_cast<uint4*>(yb + (size_t)node * 32 + j0) = pk;
}

// ---------------- FUSED gather(D=32) + matmul 32->64 ; 8 thr/node, TN=32 --------------
__global__ void __launch_bounds__(256) gmm32_64_k(
        const unsigned short* __restrict__ hb, const float* __restrict__ dinv,
        const int* __restrict__ cur, const int* __restrict__ csr,
        const float* __restrict__ W, const float* __restrict__ b,
        unsigned short* __restrict__ yb, int n) {
    constexpr int TN = 32, RS = 36;
    __shared__ float xs[TN * RS];     // 4.6 KB
    __shared__ float Ws[32 * 64];     // 8 KB
    __shared__ float bs[64];
    for (int i = threadIdx.x; i < 32 * 64; i += 256) Ws[i] = W[i];
    if (threadIdx.x < 64) bs[threadIdx.x] = b[threadIdx.x];
    int base = blockIdx.x * TN;
    {
        int nl = threadIdx.x >> 3, sub = threadIdx.x & 7;
        int rq = sub & 3, p = sub >> 2;   // row quarter (16B), edge parity
        int node = base + nl;
        if (node < n) {
            const uint4* hb4 = reinterpret_cast<const uint4*>(hb);
            float a0 = 0.f, a1 = 0.f, a2 = 0.f, a3 = 0.f, a4 = 0.f, a5 = 0.f, a6 = 0.f, a7 = 0.f;
            if (p == 0) {
                uint4 sv = hb4[(size_t)node * 4 + rq];
                a0 = bflo(sv.x); a1 = bfhi(sv.x); a2 = bflo(sv.y); a3 = bfhi(sv.y);
                a4 = bflo(sv.z); a5 = bfhi(sv.z); a6 = bflo(sv.w); a7 = bfhi(sv.w);
            }
            int e0 = node ? cur[node - 1] : 0;
            int e1 = cur[node];
            int e = e0 + p;
            for (; e + 6 < e1; e += 8) {
                int s0 = csr[e], s1 = csr[e+2], s2 = csr[e+4], s3 = csr[e+6];
                uint4 v0 = hb4[(size_t)s0 * 4 + rq];
                uint4 v1 = hb4[(size_t)s1 * 4 + rq];
                uint4 v2 = hb4[(size_t)s2 * 4 + rq];
                uint4 v3 = hb4[(size_t)s3 * 4 + rq];
                a0 += (bflo(v0.x) + bflo(v1.x)) + (bflo(v2.x) + bflo(v3.x));
                a1 += (bfhi(v0.x) + bfhi(v1.x)) + (bfhi(v2.x) + bfhi(v3.x));
                a2 += (bflo(v0.y) + bflo(v1.y)) + (bflo(v2.y) + bflo(v3.y));
                a3 += (bfhi(v0.y) + bfhi(v1.y)) + (bfhi(v2.y) + bfhi(v3.y));
                a4 += (bflo(v0.z) + bflo(v1.z)) + (bflo(v2.z) + bflo(v3.z));
                a5 += (bfhi(v0.z) + bfhi(v1.z)) + (bfhi(v2.z) + bfhi(v3.z));
                a6 += (bflo(v0.w) + bflo(v1.w)) + (bflo(v2.w) + bflo(v3.w));
                a7 += (bfhi(v0.w) + bfhi(v1.w)) + (bfhi(v2.w) + bfhi(v3.w));
            }
            for (; e < e1; e += 2) {
                uint4 v = hb4[(size_t)csr[e] * 4 + rq];
                a0 += bflo(v.x); a1 += bfhi(v.x); a2 += bflo(v.y); a3 += bfhi(v.y);
                a4 += bflo(v.z); a5 += bfhi(v.z); a6 += bflo(v.w); a7 += bfhi(v.w);
            }
            a0 += __shfl_xor(a0, 4); a1 += __shfl_xor(a1, 4); a2 += __shfl_xor(a2, 4); a3 += __shfl_xor(a3, 4);
            a4 += __shfl_xor(a4, 4); a5 += __shfl_xor(a5, 4); a6 += __shfl_xor(a6, 4); a7 += __shfl_xor(a7, 4);
            if (p == 0) {
                float di = dinv[node];
                float* dst = &xs[nl * RS + rq * 8];
                dst[0] = a0*di; dst[1] = a1*di; dst[2] = a2*di; dst[3] = a3*di;
                dst[4] = a4*di; dst[5] = a5*di; dst[6] = a6*di; dst[7] = a7*di;
            }
        }
    }
    __syncthreads();
    // matmul: 8 threads/node, 8 outputs each
    int nl = threadIdx.x >> 3, g = threadIdx.x & 7;
    int node = base + nl;
    if (node >= n) return;
    int j0 = g * 8;
    float acc[8];
#pragma unroll
    for (int j = 0; j < 8; j++) acc[j] = 0.f;
    const float* xrow = &xs[nl * RS];
#pragma unroll
    for (int k4 = 0; k4 < 8; k4++) {
        float4 xv = *reinterpret_cast<const float4*>(&xrow[k4 * 4]);
        float xk[4] = {xv.x, xv.y, xv.z, xv.w};
#pragma unroll
        for (int kk = 0; kk < 4; kk++) {
            const float* wrow = &Ws[(k4*4+kk) * 64 + j0];
#pragma unroll
            for (int j = 0; j < 8; j++) acc[j] += xk[kk] * wrow[j];
        }
    }
    float di = dinv[node];
    float o[8];
#pragma unroll
    for (int j = 0; j < 8; j++) o[j] = fmaxf(acc[j] + bs[j0 + j], 0.f) * di;
    uint4 pk;
    pk.x = (unsigned)f2bf(o[0]) | ((unsigned)f2bf(o[1]) << 16);
    pk.y = (unsigned)f2bf(o[2]) | ((unsigned)f2bf(o[3]) << 16);
    pk.z = (unsigned)f2bf(o[4]) | ((unsigned)f2bf(o[5]) << 16);
    pk.w = (unsigned)f2bf(o[6]) | ((unsigned)f2bf(o[7]) << 16);
    *reinterpret_cast<uint4*>(yb + (size_t)node * 64 + j0) = pk;
}

// ---------------- pooling helpers ----------------
__device__ inline unsigned fkey(float x) {
    unsigned u = __float_as_uint(x);
    return (u & 0x80000000u) ? ~u : (u | 0x80000000u);
}
__device__ inline float funkey(unsigned k) {
    unsigned u = (k & 0x80000000u) ? (k & 0x7FFFFFFFu) : ~k;
    return __uint_as_float(u);
}

// ---------------- fused final gather (D=4) + segment-max pool ; 8 thr/node -----------
__global__ void gather4_pool_k(const float* __restrict__ hs, const float* __restrict__ dinv,
                               const int* __restrict__ cur, const int* __restrict__ csr,
                               const float* __restrict__ b4, const int* __restrict__ batch,
                               unsigned* __restrict__ pooled, int n, int num_graphs) {
    __shared__ unsigned lds[128 * 4];
    for (int i = threadIdx.x; i < num_graphs * 4; i += blockDim.x) lds[i] = 0u;
    __syncthreads();
    int tid = blockIdx.x * blockDim.x + threadIdx.x;
    int node = tid >> 3, p = tid & 7;     // 8 edge slices
    if (node < n) {
        float4 acc = make_float4(0.f, 0.f, 0.f, 0.f);
        if (p == 0) acc = reinterpret_cast<const float4*>(hs)[node];
        int e0 = node ? cur[node - 1] : 0;
        int e1 = cur[node];
        int e = e0 + p;
        for (; e + 8 < e1; e += 16) {
            float4 v0 = reinterpret_cast<const float4*>(hs)[csr[e]];
            float4 v1 = reinterpret_cast<const float4*>(hs)[csr[e + 8]];
            acc.x += v0.x + v1.x; acc.y += v0.y + v1.y;
            acc.z += v0.z + v1.z; acc.w += v0.w + v1.w;
        }
        for (; e < e1; e += 8) {
            float4 v0 = reinterpret_cast<const float4*>(hs)[csr[e]];
            acc.x += v0.x; acc.y += v0.y; acc.z += v0.z; acc.w += v0.w;
        }
#pragma unroll
        for (int m = 1; m <= 4; m <<= 1) {
            acc.x += __shfl_xor(acc.x, m);
            acc.y += __shfl_xor(acc.y, m);
            acc.z += __shfl_xor(acc.z, m);
            acc.w += __shfl_xor(acc.w, m);
        }
        if (p == 0) {
            float di = dinv[node];
            int g = batch[node];
            atomicMax(&lds[g*4+0], fkey(acc.x * di + b4[0]));
            atomicMax(&lds[g*4+1], fkey(acc.y * di + b4[1]));
            atomicMax(&lds[g*4+2], fkey(acc.z * di + b4[2]));
            atomicMax(&lds[g*4+3], fkey(acc.w * di + b4[3]));
        }
    }
    __syncthreads();
    for (int i2 = threadIdx.x; i2 < num_graphs * 4; i2 += blockDim.x) {
        unsigned k = lds[i2];
        if (k) atomicMax(&pooled[i2], k);
    }
}

__global__ void pool_init_k(unsigned* pooled, int total) {
    int i = blockIdx.x * blockDim.x + threadIdx.x;
    if (i < total) pooled[i] = 0u;
}

__global__ void logsoftmax_k(const unsigned* __restrict__ pooled, float* __restrict__ out, int G) {
    int g = blockIdx.x * blockDim.x + threadIdx.x;
    if (g >= G) return;
    float v[4];
#pragma unroll
    for (int j = 0; j < 4; j++) v[j] = funkey(pooled[g*4+j]);
    float m = fmaxf(fmaxf(v[0], v[1]), fmaxf(v[2], v[3]));
    float s = 0.f;
#pragma unroll
    for (int j = 0; j < 4; j++) s += expf(v[j] - m);
    float l = logf(s);
#pragma unroll
    for (int j = 0; j < 4; j++) out[g*4+j] = v[j] - m - l;
}

// ---------------- LDS-tiled skinny matmul with optional bf16 in/out ----------------
template<int IN, int OUT, bool RELU, bool BIAS, bool SCALE, bool IBF, bool OBF>
__global__ void __launch_bounds__(256) matmul_k(
        const void* __restrict__ xv, const float* __restrict__ W,
        const float* __restrict__ b, const float* __restrict__ dinv,
        void* __restrict__ yv, int n) {
    constexpr int TN  = 64;
    constexpr int RS  = IN + 4;
    constexpr int OPT = OUT / 4;
    constexpr int NQ  = IN / 4;
    __shared__ float xs[TN * RS];
    __shared__ float Ws[IN * OUT];
    __shared__ float bs[OUT];

    for (int i = threadIdx.x; i < IN * OUT; i += 256) Ws[i] = W[i];
    if (BIAS) for (int i = threadIdx.x; i < OUT; i += 256) bs[i] = b[i];

    int base = blockIdx.x * TN;
    if constexpr (!IBF) {
        const float* x = (const float*)xv;
        for (int i = threadIdx.x; i < TN * NQ; i += 256) {
            int r = i / NQ, c = i % NQ;
            float4 v = make_float4(0.f, 0.f, 0.f, 0.f);
            if (base + r < n) v = reinterpret_cast<const float4*>(x + (size_t)(base + r) * IN)[c];
            *reinterpret_cast<float4*>(&xs[r * RS + c * 4]) = v;
        }
    } else {
        constexpr int NU = IN / 8;
        const uint4* x = (const uint4*)xv;
        for (int i = threadIdx.x; i < TN * NU; i += 256) {
            int r = i / NU, c = i % NU;
            uint4 v = make_uint4(0u, 0u, 0u, 0u);
            if (base + r < n) v = x[(size_t)(base + r) * NU + c];
            float* dst = &xs[r * RS + c * 8];
            dst[0] = bflo(v.x); dst[1] = bfhi(v.x);
            dst[2] = bflo(v.y); dst[3] = bfhi(v.y);
            dst[4] = bflo(v.z); dst[5] = bfhi(v.z);
            dst[6] = bflo(v.w); dst[7] = bfhi(v.w);
        }
    }
    __syncthreads();

    int node = threadIdx.x >> 2;
    int g    = threadIdx.x & 3;
    int j0   = g * OPT;
    int gnode = base + node;
    if (gnode >= n) return;

    float acc[OPT];
#pragma unroll
    for (int jj = 0; jj < OPT; jj++) acc[jj] = 0.f;

    const float* xrow = &xs[node * RS];
#pragma unroll
    for (int k4 = 0; k4 < NQ; k4++) {
        float4 xvv = *reinterpret_cast<const float4*>(&xrow[k4 * 4]);
        float xk[4] = {xvv.x, xvv.y, xvv.z, xvv.w};
#pragma unroll
        for (int kk = 0; kk < 4; kk++) {
            const float* wrow = &Ws[(k4 * 4 + kk) * OUT + j0];
#pragma unroll
            for (int jj = 0; jj < OPT; jj++)
                acc[jj] += xk[kk] * wrow[jj];
        }
    }

    float di = SCALE ? dinv[gnode] : 1.f;
    float vout[OPT];
#pragma unroll
    for (int jj = 0; jj < OPT; jj++) {
        float v = acc[jj] + (BIAS ? bs[j0 + jj] : 0.f);
        if (RELU) v = fmaxf(v, 0.f);
        if (SCALE) v *= di;
        vout[jj] = v;
    }
    if constexpr (OBF) {
        unsigned short* yr = (unsigned short*)yv + (size_t)gnode * OUT + j0;
        if constexpr (OPT % 8 == 0) {
#pragma unroll
            for (int q = 0; q < OPT / 8; q++) {
                uint4 pk;
                pk.x = (unsigned)f2bf(vout[q*8+0]) | ((unsigned)f2bf(vout[q*8+1]) << 16);
                pk.y = (unsigned)f2bf(vout[q*8+2]) | ((unsigned)f2bf(vout[q*8+3]) << 16);
                pk.z = (unsigned)f2bf(vout[q*8+4]) | ((unsigned)f2bf(vout[q*8+5]) << 16);
                pk.w = (unsigned)f2bf(vout[q*8+6]) | ((unsigned)f2bf(vout[q*8+7]) << 16);
                reinterpret_cast<uint4*>(yr)[q] = pk;
            }
        } else {
            uint2 pk;
            pk.x = (unsigned)f2bf(vout[0]) | ((unsigned)f2bf(vout[1]) << 16);
            pk.y = (unsigned)f2bf(vout[2]) | ((unsigned)f2bf(vout[3]) << 16);
            *reinterpret_cast<uint2*>(yr) = pk;
        }
    } else {
        float* yr = (float*)yv + (size_t)gnode * OUT + j0;
        if (OPT % 4 == 0) {
#pragma unroll
            for (int q = 0; q < OPT / 4; q++)
                *reinterpret_cast<float4*>(yr + q * 4) =
                    make_float4(vout[q*4+0], vout[q*4+1], vout[q*4+2], vout[q*4+3]);
        } else {
#pragma unroll
            for (int jj = 0; jj < OPT; jj++) yr[jj] = vout[jj];
        }
    }
}

// ---------------- launch ----------------
extern "C" void kernel_launch(void* const* d_in, const int* in_sizes, int n_in,
                              void* d_out, int out_size, void* d_ws, size_t ws_size,
                              hipStream_t stream) {
    const float* x     = (const float*)d_in[0];
    const int*   ei    = (const int*)d_in[1];
    const int*   batch = (const int*)d_in[2];
    const float* W1 = (const float*)d_in[3];
    const float* b1 = (const float*)d_in[4];
    const float* W2 = (const float*)d_in[5];
    const float* b2 = (const float*)d_in[6];
    const float* W3 = (const float*)d_in[7];
    const float* b3 = (const float*)d_in[8];
    const float* W4 = (const float*)d_in[9];
    const float* b4 = (const float*)d_in[10];

    const int N = in_sizes[2];          // 100000
    const int E = in_sizes[1] / 2;      // 3.2M
    const int G = 128;
    const int* row = ei;
    const int* col = ei + E;
    const int NB = DIV_UP(N, BNODES);   // 782 buckets

    // workspace layout
    float* ws    = (float*)d_ws;
    float* dinv  = ws;                              // N floats
    int*   cur   = (int*)(dinv + N);                // N ints
    int*   bhist = cur + N;                         // 1024 ints
    int*   bcur  = bhist + 1024;                    // 1024 ints
    int*   csr   = bcur + 1024;                     // E ints
    float* f16a  = (float*)(csr + E);               // N*16 floats region
    float* f16b  = f16a + (size_t)N * 16;           // N*16 floats region
    float* f32a  = f16b + (size_t)N * 16;           // N*32 floats region
    float* f32b  = f32a + (size_t)N * 32;           // N*32 floats region
    unsigned* pooled = (unsigned*)(f32b + (size_t)N * 32);  // 512
    int* part = (int*)f32a;                         // dead after csr_build
    unsigned short* hb16a = (unsigned short*)f16a;  // N*16 bf16
    unsigned short* hb16b = (unsigned short*)f16b;  // N*16 bf16
    unsigned short* hb32  = (unsigned short*)f32a;  // N*32 bf16 (after part dead)
    unsigned short* hb64  = (unsigned short*)f32b;  // N*64 bf16 = f32b region
    float* f4a = f16a;                              // N*4 fp32 (f16a free after gmm16_32)

    const int B = 256;
    const int gridM  = DIV_UP(N, 64);     // matmul_k / gmm16_32: 64 nodes/block
    const int grid32 = DIV_UP(N, 32);     // gmm32_64: 32 nodes/block
    const int grid8  = DIV_UP(8 * N, B);  // 8 threads/node kernels

    // CSR build: hist -> scan -> LDS-ranked partition -> per-bucket (tgt,src-chunk) sort
    zero_int_k<<<DIV_UP(1024, B), B, 0, stream>>>(bhist, 1024);
    bucket_hist_k<<<512, B, 0, stream>>>(col, bhist, E, NB);
    bucket_scan_k<<<1, 256, 0, stream>>>(bhist, bcur, NB);
    partition_k<<<DIV_UP(E, CHUNK_E), PTH, 0, stream>>>(row, col, bcur, part, E, NB);
    csr_build_k<<<NB, 256, 0, stream>>>(part, bcur, cur, dinv, csr, N);

    // L1: y1 = (x@W1)*dinv -> hb16b (bf16) ; gather+bias+relu+scale -> hb16a (bf16)
    matmul_k<128,16,false,false,true,false,true><<<gridM, B, 0, stream>>>(x, W1, nullptr, dinv, hb16b, N);
    gather16_bf_k<<<grid8, B, 0, stream>>>(hb16b, dinv, cur, csr, b1, hb16a, N);

    // L2 fused: gather(hb16a) + matmul 16->32 +b2,relu,*dinv -> hb32 (bf16)
    gmm16_32_k<<<gridM, B, 0, stream>>>(hb16a, dinv, cur, csr, W2, b2, hb32, N);

    // L3 fused: gather(hb32) + matmul 32->64 +b3,relu,*dinv -> hb64 (bf16)
    gmm32_64_k<<<grid32, B, 0, stream>>>(hb32, dinv, cur, csr, W3, b3, hb64, N);

    // L4: y4 = h3s@W4 (bf16 in) -> f4a (fp32) ; fused gather+pool (adds b4)
    matmul_k<64,4,false,false,false,true,false><<<gridM, B, 0, stream>>>(hb64, W4, nullptr, nullptr, f4a, N);
    pool_init_k<<<DIV_UP(G*4, B), B, 0, stream>>>(pooled, G*4);
    gather4_pool_k<<<grid8, B, 0, stream>>>(f4a, dinv, cur, csr, b4, batch, pooled, N, G);

    // log_softmax
    logsoftmax_k<<<1, 128, 0, stream>>>(pooled, (float*)d_out, G);
}